// Round 2
// baseline (2141.307 us; speedup 1.0000x reference)
//
#include <hip/hip_runtime.h>
#include <math.h>

// RecurrentSlotEncoder: B=16,K=16,N=1024,D=256,L=8
// Algebra: scores = (slots@Wqk) @ h^T      (no K-projection of h)
//          gi     = (attn@h)·rden @ WgiT + bgi, Wgi = W_ih@Wv  (no V-projection)
// Per step: attn_kernel (reads H once, 256 wgs) + chain_kernel (GRU+FFN+LN+Qk,
// 64 wgs, all weights in transposed [e][col] layout => fully coalesced streams).

#define Bn 16
#define KK 16
#define Nn 1024
#define Dn 256
#define Ln 8

// workspace float offsets
#define OFF_WQK   0          // 256*256   Wqk[d][e]
#define OFF_BQK   65536      // 256
#define OFF_WGIT  65792      // 256*768   WgiT[d][jj] = sum_c Wih[jj][c]*Wv[c][d]
#define OFF_BGI   262400     // 768
#define OFF_WHHT  263168     // 256*768   WhhT[e][jj] = Whh[jj][e]
#define OFF_W1T   459776     // 256*256   W1T[e][d] = W1[d][e]
#define OFF_W2T   525312     // 256*256
#define OFF_SLOTS 590848     // 128*256
#define OFF_QK    623616     // 128*256
#define OFF_PAV   656384     // 16*16*8*256
#define OFF_PDEN  1180672    // 16*16*8

__device__ __forceinline__ float sigmoidf_(float x) { return 1.f / (1.f + __expf(-x)); }

// P1: Wqk[d][e] = sum_a Wq[a][d]*Wk[a][e]; bqk[e] = sum_a bq[a]*Wk[a][e]
__global__ __launch_bounds__(256) void p1_kernel(
    const float* __restrict__ Wq, const float* __restrict__ bq,
    const float* __restrict__ Wk, float* __restrict__ Wqk, float* __restrict__ bqk) {
  int w = blockIdx.x, tid = threadIdx.x;
  if (w < 256) {
    float acc = 0.f;
    for (int a = 0; a < 256; ++a) acc += Wq[a * 256 + w] * Wk[a * 256 + tid];
    Wqk[w * 256 + tid] = acc;
  } else {
    float acc = 0.f;
    for (int a = 0; a < 256; ++a) acc += bq[a] * Wk[a * 256 + tid];
    bqk[tid] = acc;
  }
}

// P2: WgiT[d*768+jj] = sum_c Wih[jj][c]*Wv[c][d]; bgi[jj]=bih[jj]+sum_c Wih[jj][c]*bv[c]
__global__ __launch_bounds__(256) void p2_kernel(
    const float* __restrict__ Wih, const float* __restrict__ bih,
    const float* __restrict__ Wv, const float* __restrict__ bv,
    float* __restrict__ WgiT, float* __restrict__ bgi) {
  int d = blockIdx.x, tid = threadIdx.x;
  float a0 = 0.f, a1 = 0.f, a2 = 0.f;
  for (int c = 0; c < 256; ++c) {
    float wv = Wv[c * 256 + d];  // wave-uniform
    a0 += Wih[tid * 256 + c] * wv;
    a1 += Wih[(tid + 256) * 256 + c] * wv;
    a2 += Wih[(tid + 512) * 256 + c] * wv;
  }
  WgiT[d * 768 + tid] = a0;
  WgiT[d * 768 + 256 + tid] = a1;
  WgiT[d * 768 + 512 + tid] = a2;
  if (d < 3) {
    int jj = d * 256 + tid;
    float s = bih[jj];
    for (int c = 0; c < 256; ++c) s += Wih[jj * 256 + c] * bv[c];
    bgi[jj] = s;
  }
}

// P3: LDS tile transposes: WhhT (768x256 -> 256x768), W1T, W2T (256x256)
__global__ __launch_bounds__(256) void p3_kernel(
    const float* __restrict__ Whh, const float* __restrict__ W1,
    const float* __restrict__ W2, float* __restrict__ WhhT,
    float* __restrict__ W1T, float* __restrict__ W2T) {
  __shared__ float tile[32][33];
  int wg = blockIdx.x, tid = threadIdx.x;
  const float* in; float* out; int R, C, tr, tc;
  if (wg < 192)      { in = Whh; out = WhhT; R = 768; C = 256; wg -= 0;   tr = wg >> 3; tc = wg & 7; }
  else if (wg < 256) { in = W1;  out = W1T;  R = 256; C = 256; wg -= 192; tr = wg >> 3; tc = wg & 7; }
  else               { in = W2;  out = W2T;  R = 256; C = 256; wg -= 256; tr = wg >> 3; tc = wg & 7; }
  int r = tid >> 5, c = tid & 31;
#pragma unroll
  for (int k = 0; k < 4; ++k)
    tile[r + 8 * k][c] = in[(tr * 32 + r + 8 * k) * C + tc * 32 + c];
  __syncthreads();
#pragma unroll
  for (int k = 0; k < 4; ++k)
    out[(tc * 32 + r + 8 * k) * R + tr * 32 + c] = tile[c][r + 8 * k];
}

__global__ __launch_bounds__(256) void init_slots_kernel(
    const float* __restrict__ eps, const float* __restrict__ mu,
    const float* __restrict__ lsig, float* __restrict__ slots) {
  int idx = blockIdx.x * 256 + threadIdx.x;  // 32768
  int r = idx & 2047;
  slots[idx] = mu[r] + expf(lsig[r]) * eps[idx];
}

// Qk = slots @ Wqk + bqk  (t=0 only; per-step Qk is produced by chain_kernel)
__global__ __launch_bounds__(256) void qk0_kernel(
    const float* __restrict__ Wqk, const float* __restrict__ bqk,
    const float* __restrict__ slots, float* __restrict__ Qkout) {
  __shared__ float sl_s[2048];
  int j = blockIdx.x & 7, b = blockIdx.x >> 3, tid = threadIdx.x;
  for (int k = 0; k < 8; ++k) sl_s[tid + k * 256] = slots[b * 2048 + tid + k * 256];
  __syncthreads();
  int l = tid >> 5, ee = j * 32 + (tid & 31);
  float acc = bqk[ee];
  for (int d = 0; d < 256; ++d) acc += sl_s[l * 256 + d] * Wqk[d * 256 + ee];
  Qkout[b * 2048 + l * 256 + ee] = acc;
}

// Fused attention: per (b, 64-row tile): exp-scores (unnormalized Beta),
// partial denom, partial attn@H. H staged once in LDS (row stride 258).
__global__ __launch_bounds__(256) void attn_kernel(
    const float* __restrict__ H, const float* __restrict__ Qk,
    float* __restrict__ beta_out, float* __restrict__ par_av,
    float* __restrict__ par_den, int t) {
  __shared__ float h_s[32 * 258];
  __shared__ float qk_s[Ln * Dn];
  __shared__ float e_s[256];
  __shared__ float red[256];
  int tile = blockIdx.x, b = blockIdx.y, tid = threadIdx.x;
  for (int k = 0; k < 8; ++k) qk_s[tid + k * 256] = Qk[b * 2048 + tid + k * 256];
  int l = tid >> 5, row = tid & 31;
  float av[8];
#pragma unroll
  for (int i = 0; i < 8; ++i) av[i] = 0.f;
  float dloc = 0.f;
  const float* Hbase = H + (((long)b * KK + t) * Nn + tile * 64) * Dn;
  for (int sub = 0; sub < 2; ++sub) {
    __syncthreads();
    const float4* src = (const float4*)(Hbase + sub * 32 * 256);
    for (int k = 0; k < 8; ++k) {
      int idx4 = tid + k * 256;
      int r = idx4 >> 6, d4 = idx4 & 63;
      float4 v = src[idx4];
      float* dst = &h_s[r * 258 + d4 * 4];
      ((float2*)dst)[0] = make_float2(v.x, v.y);
      ((float2*)dst)[1] = make_float2(v.z, v.w);
    }
    __syncthreads();
    {
      const float2* hr2 = (const float2*)(&h_s[row * 258]);
      const float2* qr2 = (const float2*)(&qk_s[l * 256]);
      float acc = 0.f;
#pragma unroll 8
      for (int e = 0; e < 128; ++e) {
        float2 hv = hr2[e], qv = qr2[e];
        acc += hv.x * qv.x + hv.y * qv.y;
      }
      float ev = __expf(acc * 0.0625f);  // 1/sqrt(256); no max-sub (|s| small)
      e_s[tid] = ev;
      dloc += ev;
      beta_out[(((long)b * KK + t) * Ln + l) * Nn + tile * 64 + sub * 32 + row] = ev;
    }
    __syncthreads();
    for (int rr = 0; rr < 32; ++rr) {
      float hv = h_s[rr * 258 + tid];
#pragma unroll
      for (int i = 0; i < 8; ++i) av[i] += e_s[i * 32 + rr] * hv;
    }
  }
  long pbase = (long)(b * 16 + tile) * 2048;
#pragma unroll
  for (int i = 0; i < 8; ++i) par_av[pbase + i * 256 + tid] = av[i];
  red[tid] = dloc;
  __syncthreads();
  if (tid < 8) {
    float s = 0.f;
    for (int i = 0; i < 32; ++i) s += red[tid * 32 + i];
    par_den[(b * 16 + tile) * 8 + tid] = s;
  }
}

// Fused chain: reduce partials -> GRU -> FFN -> +res -> LN -> write S/slots -> Qk.
// One wg per (b, slot-pair): 64 wgs, 256 threads (tid = output column).
// All weight streams coalesced via transposed layouts.
__global__ __launch_bounds__(256) void chain_kernel(
    const float* __restrict__ WgiT, const float* __restrict__ bgi,
    const float* __restrict__ WhhT, const float* __restrict__ bhh,
    const float* __restrict__ W1T, const float* __restrict__ b1,
    const float* __restrict__ W2T, const float* __restrict__ b2,
    const float* __restrict__ Wqk, const float* __restrict__ bqk,
    const float* __restrict__ ln_g, const float* __restrict__ ln_b,
    const float* __restrict__ par_av, const float* __restrict__ par_den,
    float* __restrict__ slots, float* __restrict__ S, float* __restrict__ Beta,
    float* __restrict__ Qk, int t) {
  __shared__ float upd_s[2][256], sl_s[2][256], s2_s[2][256], f_s[2][256], s3_s[2][256];
  __shared__ float red_s[2][8];
  int b = blockIdx.x >> 2, lp = blockIdx.x & 3, tid = threadIdx.x;
  int l0 = lp * 2, l1 = l0 + 1;

  float d0 = 0.f, d1 = 0.f;
  for (int tl = 0; tl < 16; ++tl) {
    d0 += par_den[(b * 16 + tl) * 8 + l0];
    d1 += par_den[(b * 16 + tl) * 8 + l1];
  }
  float rd0 = 1.f / d0, rd1 = 1.f / d1;
  float a0 = 0.f, a1 = 0.f;
  for (int tl = 0; tl < 16; ++tl) {
    long base = (long)(b * 16 + tl) * 2048;
    a0 += par_av[base + l0 * 256 + tid];
    a1 += par_av[base + l1 * 256 + tid];
  }
  upd_s[0][tid] = a0 * rd0;
  upd_s[1][tid] = a1 * rd1;
  sl_s[0][tid] = slots[b * 2048 + l0 * 256 + tid];
  sl_s[1][tid] = slots[b * 2048 + l1 * 256 + tid];
  __syncthreads();

  // Beta normalize (independent of the rest)
  {
    long bb0 = (((long)b * KK + t) * Ln + l0) * Nn;
    long bb1 = (((long)b * KK + t) * Ln + l1) * Nn;
#pragma unroll
    for (int k = 0; k < 4; ++k) Beta[bb0 + k * 256 + tid] *= rd0;
#pragma unroll
    for (int k = 0; k < 4; ++k) Beta[bb1 + k * 256 + tid] *= rd1;
  }

  // GRU: 6 coalesced weight streams, 2 rows per load
  float ir0 = 0, iz0 = 0, in0 = 0, hr0 = 0, hz0 = 0, hn0 = 0;
  float ir1 = 0, iz1 = 0, in1 = 0, hr1 = 0, hz1 = 0, hn1 = 0;
#pragma unroll 2
  for (int e = 0; e < 256; ++e) {
    float u0 = upd_s[0][e], u1 = upd_s[1][e];
    float s0 = sl_s[0][e], s1 = sl_s[1][e];
    const float* wg = WgiT + e * 768;
    const float* wh = WhhT + e * 768;
    float w;
    w = wg[tid];       ir0 += u0 * w; ir1 += u1 * w;
    w = wg[256 + tid]; iz0 += u0 * w; iz1 += u1 * w;
    w = wg[512 + tid]; in0 += u0 * w; in1 += u1 * w;
    w = wh[tid];       hr0 += s0 * w; hr1 += s1 * w;
    w = wh[256 + tid]; hz0 += s0 * w; hz1 += s1 * w;
    w = wh[512 + tid]; hn0 += s0 * w; hn1 += s1 * w;
  }
  float bg_r = bgi[tid], bg_z = bgi[256 + tid], bg_n = bgi[512 + tid];
  float bh_r = bhh[tid], bh_z = bhh[256 + tid], bh_n = bhh[512 + tid];
  float r0 = sigmoidf_(ir0 + bg_r + hr0 + bh_r);
  float z0 = sigmoidf_(iz0 + bg_z + hz0 + bh_z);
  float n0 = tanhf(in0 + bg_n + r0 * (hn0 + bh_n));
  float s2v0 = (1.f - z0) * n0 + z0 * sl_s[0][tid];
  float r1 = sigmoidf_(ir1 + bg_r + hr1 + bh_r);
  float z1 = sigmoidf_(iz1 + bg_z + hz1 + bh_z);
  float n1 = tanhf(in1 + bg_n + r1 * (hn1 + bh_n));
  float s2v1 = (1.f - z1) * n1 + z1 * sl_s[1][tid];
  s2_s[0][tid] = s2v0;
  s2_s[1][tid] = s2v1;
  __syncthreads();

  // f1 = relu(s2 @ W1^T + b1)
  float f0 = b1[tid], f1v = b1[tid];
#pragma unroll 4
  for (int e = 0; e < 256; ++e) {
    float w = W1T[e * 256 + tid];
    f0 += s2_s[0][e] * w;
    f1v += s2_s[1][e] * w;
  }
  f_s[0][tid] = fmaxf(f0, 0.f);
  f_s[1][tid] = fmaxf(f1v, 0.f);
  __syncthreads();

  // x = s2 + f1 @ W2^T + b2
  float x0 = b2[tid], x1 = b2[tid];
#pragma unroll 4
  for (int e = 0; e < 256; ++e) {
    float w = W2T[e * 256 + tid];
    x0 += f_s[0][e] * w;
    x1 += f_s[1][e] * w;
  }
  x0 += s2v0;
  x1 += s2v1;

  // LayerNorm stats over 256 cols (wave shuffle + LDS combine)
  float s0r = x0, q0r = x0 * x0, s1r = x1, q1r = x1 * x1;
#pragma unroll
  for (int m = 1; m < 64; m <<= 1) {
    s0r += __shfl_xor(s0r, m);
    q0r += __shfl_xor(q0r, m);
    s1r += __shfl_xor(s1r, m);
    q1r += __shfl_xor(q1r, m);
  }
  int wv = tid >> 6;
  if ((tid & 63) == 0) {
    red_s[0][wv] = s0r; red_s[0][4 + wv] = q0r;
    red_s[1][wv] = s1r; red_s[1][4 + wv] = q1r;
  }
  __syncthreads();
  float m0 = (red_s[0][0] + red_s[0][1] + red_s[0][2] + red_s[0][3]) * (1.f / 256.f);
  float v0 = (red_s[0][4] + red_s[0][5] + red_s[0][6] + red_s[0][7]) * (1.f / 256.f) - m0 * m0;
  float m1 = (red_s[1][0] + red_s[1][1] + red_s[1][2] + red_s[1][3]) * (1.f / 256.f);
  float v1 = (red_s[1][4] + red_s[1][5] + red_s[1][6] + red_s[1][7]) * (1.f / 256.f) - m1 * m1;
  float g = ln_g[tid], be = ln_b[tid];
  float s3v0 = (x0 - m0) * rsqrtf(v0 + 1e-5f) * g + be;
  float s3v1 = (x1 - m1) * rsqrtf(v1 + 1e-5f) * g + be;
  long sb = ((long)b * KK + t) * 2048;
  S[sb + l0 * 256 + tid] = s3v0;
  S[sb + l1 * 256 + tid] = s3v1;
  slots[b * 2048 + l0 * 256 + tid] = s3v0;
  slots[b * 2048 + l1 * 256 + tid] = s3v1;
  s3_s[0][tid] = s3v0;
  s3_s[1][tid] = s3v1;
  __syncthreads();

  // next-step Qk = s3 @ Wqk + bqk
  float q0a = bqk[tid], q1a = bqk[tid];
#pragma unroll 4
  for (int d = 0; d < 256; ++d) {
    float w = Wqk[d * 256 + tid];
    q0a += s3_s[0][d] * w;
    q1a += s3_s[1][d] * w;
  }
  Qk[b * 2048 + l0 * 256 + tid] = q0a;
  Qk[b * 2048 + l1 * 256 + tid] = q1a;
}

extern "C" void kernel_launch(void* const* d_in, const int* in_sizes, int n_in,
                              void* d_out, int out_size, void* d_ws, size_t ws_size,
                              hipStream_t stream) {
  const float* H    = (const float*)d_in[0];
  const float* eps  = (const float*)d_in[1];
  const float* mu   = (const float*)d_in[2];
  const float* lsig = (const float*)d_in[3];
  const float* Wq   = (const float*)d_in[4];
  const float* bq   = (const float*)d_in[5];
  const float* Wk   = (const float*)d_in[6];
  // d_in[7] = bk: constant per softmax row -> drops out
  const float* Wv   = (const float*)d_in[8];
  const float* bv   = (const float*)d_in[9];
  const float* Wih  = (const float*)d_in[10];
  const float* bih  = (const float*)d_in[11];
  const float* Whh  = (const float*)d_in[12];
  const float* bhh  = (const float*)d_in[13];
  const float* W1   = (const float*)d_in[14];
  const float* b1   = (const float*)d_in[15];
  const float* W2   = (const float*)d_in[16];
  const float* b2   = (const float*)d_in[17];
  const float* ln_g = (const float*)d_in[18];
  const float* ln_b = (const float*)d_in[19];

  float* out = (float*)d_out;
  float* S    = out;                            // [B,K,L,D]
  float* Beta = out + (long)Bn * KK * Ln * Dn;  // [B,K,L,N]

  float* ws = (float*)d_ws;
  float* Wqk   = ws + OFF_WQK;
  float* bqk   = ws + OFF_BQK;
  float* WgiT  = ws + OFF_WGIT;
  float* bgi   = ws + OFF_BGI;
  float* WhhT  = ws + OFF_WHHT;
  float* W1T   = ws + OFF_W1T;
  float* W2T   = ws + OFF_W2T;
  float* slots = ws + OFF_SLOTS;
  float* Qk    = ws + OFF_QK;
  float* pav   = ws + OFF_PAV;
  float* pden  = ws + OFF_PDEN;

  p1_kernel<<<257, 256, 0, stream>>>(Wq, bq, Wk, Wqk, bqk);
  p2_kernel<<<256, 256, 0, stream>>>(Wih, bih, Wv, bv, WgiT, bgi);
  p3_kernel<<<320, 256, 0, stream>>>(Whh, W1, W2, WhhT, W1T, W2T);
  init_slots_kernel<<<128, 256, 0, stream>>>(eps, mu, lsig, slots);
  qk0_kernel<<<128, 256, 0, stream>>>(Wqk, bqk, slots, Qk);

  for (int t = 0; t < KK; ++t) {
    attn_kernel<<<dim3(16, 16), 256, 0, stream>>>(H, Qk, Beta, pav, pden, t);
    chain_kernel<<<64, 256, 0, stream>>>(WgiT, bgi, WhhT, bhh, W1T, b1, W2T, b2,
                                         Wqk, bqk, ln_g, ln_b, pav, pden,
                                         slots, S, Beta, Qk, t);
  }
}

// Round 3
// 1066.402 us; speedup vs baseline: 2.0080x; 2.0080x over previous
//
#include <hip/hip_runtime.h>
#include <math.h>

// RecurrentSlotEncoder: B=16,K=16,N=1024,D=256,L=8
// Algebra: scores = (slots@Wqk) @ h^T      (no K-projection of h)
//          gi     = (attn@h)·rden @ WgiT + bgi, Wgi = W_ih@Wv  (no V-projection)
// R3 structure: per step = attn (512 wgs, 32-row tiles) + chain (128 wgs x 1024
// threads, every K=256 GEMV split 4-way across thread-groups -> 64-iter loops,
// 4 waves/SIMD to hide L2 latency). All weight streams coalesced (transposed).

#define Bn 16
#define KK 16
#define Nn 1024
#define Dn 256
#define Ln 8

// workspace float offsets
#define OFF_WQK   0          // 256*256   Wqk[d][e]
#define OFF_BQK   65536      // 256
#define OFF_WGIT  65792      // 256*768   WgiT[e][jj] = sum_c Wih[jj][c]*Wv[c][e]
#define OFF_BGI   262400     // 768
#define OFF_WHHT  263168     // 256*768   WhhT[e][jj] = Whh[jj][e]
#define OFF_W1T   459776     // 256*256
#define OFF_W2T   525312     // 256*256
#define OFF_SLOTS 590848     // 128*256
#define OFF_QK    623616     // 128*256
#define OFF_PAV   656384     // 16*32*8*256 = 1048576
#define OFF_PDEN  1704960    // 16*32*8 = 4096

__device__ __forceinline__ float sigmoidf_(float x) { return 1.f / (1.f + __expf(-x)); }

// P1: Wqk[d][e] = sum_a Wq[a][d]*Wk[a][e]; bqk[e] = sum_a bq[a]*Wk[a][e]
__global__ __launch_bounds__(256) void p1_kernel(
    const float* __restrict__ Wq, const float* __restrict__ bq,
    const float* __restrict__ Wk, float* __restrict__ Wqk, float* __restrict__ bqk) {
  int w = blockIdx.x, tid = threadIdx.x;
  if (w < 256) {
    float acc = 0.f;
    for (int a = 0; a < 256; ++a) acc += Wq[a * 256 + w] * Wk[a * 256 + tid];
    Wqk[w * 256 + tid] = acc;
  } else {
    float acc = 0.f;
    for (int a = 0; a < 256; ++a) acc += bq[a] * Wk[a * 256 + tid];
    bqk[tid] = acc;
  }
}

// P2: WgiT[e*768+jj] = sum_c Wih[jj][c]*Wv[c][e]; bgi[jj]=bih[jj]+sum_c Wih[jj][c]*bv[c]
__global__ __launch_bounds__(256) void p2_kernel(
    const float* __restrict__ Wih, const float* __restrict__ bih,
    const float* __restrict__ Wv, const float* __restrict__ bv,
    float* __restrict__ WgiT, float* __restrict__ bgi) {
  int d = blockIdx.x, tid = threadIdx.x;
  float a0 = 0.f, a1 = 0.f, a2 = 0.f;
  for (int c = 0; c < 256; ++c) {
    float wv = Wv[c * 256 + d];  // wave-uniform
    a0 += Wih[tid * 256 + c] * wv;
    a1 += Wih[(tid + 256) * 256 + c] * wv;
    a2 += Wih[(tid + 512) * 256 + c] * wv;
  }
  WgiT[d * 768 + tid] = a0;
  WgiT[d * 768 + 256 + tid] = a1;
  WgiT[d * 768 + 512 + tid] = a2;
  if (d < 3) {
    int jj = d * 256 + tid;
    float s = bih[jj];
    for (int c = 0; c < 256; ++c) s += Wih[jj * 256 + c] * bv[c];
    bgi[jj] = s;
  }
}

// P3: LDS tile transposes: WhhT (768x256 -> 256x768), W1T, W2T (256x256)
__global__ __launch_bounds__(256) void p3_kernel(
    const float* __restrict__ Whh, const float* __restrict__ W1,
    const float* __restrict__ W2, float* __restrict__ WhhT,
    float* __restrict__ W1T, float* __restrict__ W2T) {
  __shared__ float tile[32][33];
  int wg = blockIdx.x, tid = threadIdx.x;
  const float* in; float* out; int R, C, tr, tc;
  if (wg < 192)      { in = Whh; out = WhhT; R = 768; C = 256; wg -= 0;   tr = wg >> 3; tc = wg & 7; }
  else if (wg < 256) { in = W1;  out = W1T;  R = 256; C = 256; wg -= 192; tr = wg >> 3; tc = wg & 7; }
  else               { in = W2;  out = W2T;  R = 256; C = 256; wg -= 256; tr = wg >> 3; tc = wg & 7; }
  int r = tid >> 5, c = tid & 31;
#pragma unroll
  for (int k = 0; k < 4; ++k)
    tile[r + 8 * k][c] = in[(tr * 32 + r + 8 * k) * C + tc * 32 + c];
  __syncthreads();
#pragma unroll
  for (int k = 0; k < 4; ++k)
    out[(tc * 32 + r + 8 * k) * R + tr * 32 + c] = tile[c][r + 8 * k];
}

__global__ __launch_bounds__(256) void init_slots_kernel(
    const float* __restrict__ eps, const float* __restrict__ mu,
    const float* __restrict__ lsig, float* __restrict__ slots) {
  int idx = blockIdx.x * 256 + threadIdx.x;  // 32768
  int r = idx & 2047;
  slots[idx] = mu[r] + expf(lsig[r]) * eps[idx];
}

// Qk = slots @ Wqk + bqk (t=0 only)
__global__ __launch_bounds__(256) void qk0_kernel(
    const float* __restrict__ Wqk, const float* __restrict__ bqk,
    const float* __restrict__ slots, float* __restrict__ Qkout) {
  __shared__ float sl_s[2048];
  int j = blockIdx.x & 7, b = blockIdx.x >> 3, tid = threadIdx.x;
  for (int k = 0; k < 8; ++k) sl_s[tid + k * 256] = slots[b * 2048 + tid + k * 256];
  __syncthreads();
  int l = tid >> 5, ee = j * 32 + (tid & 31);
  float acc = bqk[ee];
  for (int d = 0; d < 256; ++d) acc += sl_s[l * 256 + d] * Wqk[d * 256 + ee];
  Qkout[b * 2048 + l * 256 + ee] = acc;
}

// Fused attention: wg = (tile32, b), grid (32,16). Stages 32 rows of H in LDS,
// computes exp-scores (unnormalized Beta), per-tile denom, per-tile attn@H.
__global__ __launch_bounds__(256) void attn_kernel(
    const float* __restrict__ H, const float* __restrict__ Qk,
    float* __restrict__ beta_out, float* __restrict__ par_av,
    float* __restrict__ par_den, int t) {
  __shared__ float h_s[32 * 258];
  __shared__ float qk_s[Ln * Dn];
  __shared__ float e_s[256];
  __shared__ float red[256];
  int tile = blockIdx.x, b = blockIdx.y, tid = threadIdx.x;
#pragma unroll
  for (int k = 0; k < 8; ++k) qk_s[tid + k * 256] = Qk[b * 2048 + tid + k * 256];
  const float* Hbase = H + (((long)b * KK + t) * Nn + tile * 32) * Dn;
  const float4* src = (const float4*)Hbase;
#pragma unroll
  for (int k = 0; k < 8; ++k) {
    int idx4 = tid + k * 256;  // 0..2047 coalesced
    int r = idx4 >> 6, d4 = idx4 & 63;
    float4 v = src[idx4];
    float* dst = &h_s[r * 258 + d4 * 4];
    ((float2*)dst)[0] = make_float2(v.x, v.y);
    ((float2*)dst)[1] = make_float2(v.z, v.w);
  }
  __syncthreads();
  int l = tid >> 5, row = tid & 31;
  // phase A: scores
  {
    const float2* hr2 = (const float2*)(&h_s[row * 258]);
    const float2* qr2 = (const float2*)(&qk_s[l * 256]);
    float acc = 0.f;
#pragma unroll 8
    for (int e = 0; e < 128; ++e) {
      float2 hv = hr2[e], qv = qr2[e];
      acc += hv.x * qv.x + hv.y * qv.y;
    }
    float ev = __expf(acc * 0.0625f);  // 1/sqrt(256); no max-sub (|s| small)
    e_s[tid] = ev;
    red[tid] = ev;
    beta_out[(((long)b * KK + t) * Ln + l) * Nn + tile * 32 + row] = ev;
  }
  __syncthreads();
  if (tid < 8) {
    float s = 0.f;
    for (int i = 0; i < 32; ++i) s += red[tid * 32 + i];
    par_den[(b * 32 + tile) * 8 + tid] = s;
  }
  // phase B: av[l] += e[l,row] * h[row, d=tid]
  float av[8];
#pragma unroll
  for (int i = 0; i < 8; ++i) av[i] = 0.f;
  for (int rr = 0; rr < 32; ++rr) {
    float hv = h_s[rr * 258 + tid];
#pragma unroll
    for (int i = 0; i < 8; ++i) av[i] += e_s[i * 32 + rr] * hv;
  }
  long pbase = (long)(b * 32 + tile) * 2048;
#pragma unroll
  for (int i = 0; i < 8; ++i) par_av[pbase + i * 256 + tid] = av[i];
}

// Fused chain: wg = (b,l), 128 wgs x 1024 threads (kc = tid>>8 splits K=256
// into 4 chunks of 64; c = tid&255 is the output column). Phases:
// reduce -> GRU -> f1 -> ffn+LN -> Qk, LDS tree-reduce between K-chunks.
__global__ __launch_bounds__(1024) void chain_kernel(
    const float* __restrict__ WgiT, const float* __restrict__ bgi,
    const float* __restrict__ WhhT, const float* __restrict__ bhh,
    const float* __restrict__ W1T, const float* __restrict__ b1,
    const float* __restrict__ W2T, const float* __restrict__ b2,
    const float* __restrict__ Wqk, const float* __restrict__ bqk,
    const float* __restrict__ ln_g, const float* __restrict__ ln_b,
    const float* __restrict__ par_av, const float* __restrict__ par_den,
    float* __restrict__ slots, float* __restrict__ S, float* __restrict__ Beta,
    float* __restrict__ Qk, int t) {
  __shared__ float upd_s[256], sl_s[256], s2_s[256], f_s[256], s3_s[256];
  __shared__ float red6[6][4][256];
  __shared__ float den_inv;
  __shared__ float lnred[8];
  int b = blockIdx.x >> 3, l = blockIdx.x & 7;
  int tid = threadIdx.x, kc = tid >> 8, c = tid & 255;

  // phase 0: reduce par_av (32 tiles, 8 per kc) + den + stage slots row
  {
    float ps = 0.f;
    long pvb = (long)(b * 32) * 2048 + l * 256 + c;
#pragma unroll
    for (int i = 0; i < 8; ++i) ps += par_av[pvb + (long)(kc * 8 + i) * 2048];
    red6[0][kc][c] = ps;
    float dv = 0.f;
    if (tid < 64) {
      if (tid < 32) dv = par_den[(b * 32 + tid) * 8 + l];
#pragma unroll
      for (int m = 1; m < 64; m <<= 1) dv += __shfl_xor(dv, m);
      if (tid == 0) den_inv = 1.f / dv;
    }
    if (kc == 1) sl_s[c] = slots[b * 2048 + l * 256 + c];
  }
  __syncthreads();
  float rd = den_inv;
  if (kc == 0)
    upd_s[c] = (red6[0][0][c] + red6[0][1][c] + red6[0][2][c] + red6[0][3][c]) * rd;
  // Beta normalize: 1024 threads, one element each
  {
    long bb = (((long)b * KK + t) * Ln + l) * Nn;
    Beta[bb + tid] *= rd;
  }
  __syncthreads();

  // phase 1: GRU partial dots (6 streams, K-chunk of 64)
  {
    float ir = 0, iz = 0, in_ = 0, hr = 0, hz = 0, hn = 0;
#pragma unroll 4
    for (int i = 0; i < 64; ++i) {
      int e = kc * 64 + i;
      float u = upd_s[e], s = sl_s[e];
      const float* wg = WgiT + (long)e * 768;
      const float* wh = WhhT + (long)e * 768;
      ir += u * wg[c];       iz += u * wg[256 + c];  in_ += u * wg[512 + c];
      hr += s * wh[c];       hz += s * wh[256 + c];  hn  += s * wh[512 + c];
    }
    red6[0][kc][c] = ir; red6[1][kc][c] = iz; red6[2][kc][c] = in_;
    red6[3][kc][c] = hr; red6[4][kc][c] = hz; red6[5][kc][c] = hn;
  }
  __syncthreads();
  if (kc == 0) {
    float tir = red6[0][0][c] + red6[0][1][c] + red6[0][2][c] + red6[0][3][c] + bgi[c];
    float tiz = red6[1][0][c] + red6[1][1][c] + red6[1][2][c] + red6[1][3][c] + bgi[256 + c];
    float tin = red6[2][0][c] + red6[2][1][c] + red6[2][2][c] + red6[2][3][c] + bgi[512 + c];
    float thr = red6[3][0][c] + red6[3][1][c] + red6[3][2][c] + red6[3][3][c] + bhh[c];
    float thz = red6[4][0][c] + red6[4][1][c] + red6[4][2][c] + red6[4][3][c] + bhh[256 + c];
    float thn = red6[5][0][c] + red6[5][1][c] + red6[5][2][c] + red6[5][3][c] + bhh[512 + c];
    float r = sigmoidf_(tir + thr);
    float z = sigmoidf_(tiz + thz);
    float n = tanhf(tin + r * thn);
    s2_s[c] = (1.f - z) * n + z * sl_s[c];
  }
  __syncthreads();

  // phase 2: f1 = relu(s2 @ W1^T + b1)
  {
    float f = 0.f;
#pragma unroll 4
    for (int i = 0; i < 64; ++i) {
      int e = kc * 64 + i;
      f += s2_s[e] * W1T[e * 256 + c];
    }
    red6[0][kc][c] = f;
  }
  __syncthreads();
  if (kc == 0)
    f_s[c] = fmaxf(red6[0][0][c] + red6[0][1][c] + red6[0][2][c] + red6[0][3][c] + b1[c], 0.f);
  __syncthreads();

  // phase 3: x = s2 + f1 @ W2^T + b2, then LayerNorm
  {
    float x = 0.f;
#pragma unroll 4
    for (int i = 0; i < 64; ++i) {
      int e = kc * 64 + i;
      x += f_s[e] * W2T[e * 256 + c];
    }
    red6[1][kc][c] = x;
  }
  __syncthreads();
  float xv = 0.f;
  if (kc == 0) {
    xv = red6[1][0][c] + red6[1][1][c] + red6[1][2][c] + red6[1][3][c] + b2[c] + s2_s[c];
    float sr = xv, qr = xv * xv;
#pragma unroll
    for (int m = 1; m < 64; m <<= 1) {
      sr += __shfl_xor(sr, m);
      qr += __shfl_xor(qr, m);
    }
    if ((c & 63) == 0) { lnred[c >> 6] = sr; lnred[4 + (c >> 6)] = qr; }
  }
  __syncthreads();
  if (kc == 0) {
    float m = (lnred[0] + lnred[1] + lnred[2] + lnred[3]) * (1.f / 256.f);
    float v = (lnred[4] + lnred[5] + lnred[6] + lnred[7]) * (1.f / 256.f) - m * m;
    float s3 = (xv - m) * rsqrtf(v + 1e-5f) * ln_g[c] + ln_b[c];
    s3_s[c] = s3;
    S[(((long)b * KK + t) * Ln + l) * Dn + c] = s3;
    slots[b * 2048 + l * 256 + c] = s3;
  }
  __syncthreads();

  // phase 4: next Qk = s3 @ Wqk + bqk
  {
    float q = 0.f;
#pragma unroll 4
    for (int i = 0; i < 64; ++i) {
      int e = kc * 64 + i;
      q += s3_s[e] * Wqk[e * 256 + c];
    }
    red6[0][kc][c] = q;
  }
  __syncthreads();
  if (kc == 0)
    Qk[b * 2048 + l * 256 + c] =
        red6[0][0][c] + red6[0][1][c] + red6[0][2][c] + red6[0][3][c] + bqk[c];
}

extern "C" void kernel_launch(void* const* d_in, const int* in_sizes, int n_in,
                              void* d_out, int out_size, void* d_ws, size_t ws_size,
                              hipStream_t stream) {
  const float* H    = (const float*)d_in[0];
  const float* eps  = (const float*)d_in[1];
  const float* mu   = (const float*)d_in[2];
  const float* lsig = (const float*)d_in[3];
  const float* Wq   = (const float*)d_in[4];
  const float* bq   = (const float*)d_in[5];
  const float* Wk   = (const float*)d_in[6];
  // d_in[7] = bk: constant per softmax row -> drops out
  const float* Wv   = (const float*)d_in[8];
  const float* bv   = (const float*)d_in[9];
  const float* Wih  = (const float*)d_in[10];
  const float* bih  = (const float*)d_in[11];
  const float* Whh  = (const float*)d_in[12];
  const float* bhh  = (const float*)d_in[13];
  const float* W1   = (const float*)d_in[14];
  const float* b1   = (const float*)d_in[15];
  const float* W2   = (const float*)d_in[16];
  const float* b2   = (const float*)d_in[17];
  const float* ln_g = (const float*)d_in[18];
  const float* ln_b = (const float*)d_in[19];

  float* out = (float*)d_out;
  float* S    = out;                            // [B,K,L,D]
  float* Beta = out + (long)Bn * KK * Ln * Dn;  // [B,K,L,N]

  float* ws = (float*)d_ws;
  float* Wqk   = ws + OFF_WQK;
  float* bqk   = ws + OFF_BQK;
  float* WgiT  = ws + OFF_WGIT;
  float* bgi   = ws + OFF_BGI;
  float* WhhT  = ws + OFF_WHHT;
  float* W1T   = ws + OFF_W1T;
  float* W2T   = ws + OFF_W2T;
  float* slots = ws + OFF_SLOTS;
  float* Qk    = ws + OFF_QK;
  float* pav   = ws + OFF_PAV;
  float* pden  = ws + OFF_PDEN;

  p1_kernel<<<257, 256, 0, stream>>>(Wq, bq, Wk, Wqk, bqk);
  p2_kernel<<<256, 256, 0, stream>>>(Wih, bih, Wv, bv, WgiT, bgi);
  p3_kernel<<<320, 256, 0, stream>>>(Whh, W1, W2, WhhT, W1T, W2T);
  init_slots_kernel<<<128, 256, 0, stream>>>(eps, mu, lsig, slots);
  qk0_kernel<<<128, 256, 0, stream>>>(Wqk, bqk, slots, Qk);

  for (int t = 0; t < KK; ++t) {
    attn_kernel<<<dim3(32, 16), 256, 0, stream>>>(H, Qk, Beta, pav, pden, t);
    chain_kernel<<<128, 1024, 0, stream>>>(WgiT, bgi, WhhT, bhh, W1T, b1, W2T, b2,
                                           Wqk, bqk, ln_g, ln_b, pav, pden,
                                           slots, S, Beta, Qk, t);
  }
}